// Round 21
// baseline (238.582 us; speedup 1.0000x reference)
//
#include <hip/hip_runtime.h>
#include <math.h>

constexpr int CW = 3125;   // valid width
constexpr int CC = 256;    // channels
constexpr int CB = 4;      // batch
constexpr int NHh = 8;     // heads
constexpr int KDd = 64;    // qk head dim
constexpr int HDd = 32;    // v head dim
constexpr int QROW = 64;   // q/k image row stride in shorts
constexpr int VROW = 256;  // v buffer row stride in floats

typedef __attribute__((ext_vector_type(8))) short short8;
typedef __attribute__((ext_vector_type(4))) float f32x4;
typedef __attribute__((ext_vector_type(2))) float f32x2;
typedef __attribute__((ext_vector_type(4))) unsigned int uint4v;
typedef __attribute__((ext_vector_type(2))) unsigned int uint2v;

__device__ inline unsigned short f2bf(float x) {
  unsigned int u = __float_as_uint(x);
  unsigned int r = u + 0x7FFFu + ((u >> 16) & 1u);
  return (unsigned short)(r >> 16);
}

// x (b,256,CW) -> xcur (b,CW,256) position-major AND Ximg staged bf16 image
// Ximg: [ptile][ktile=8][kchunk=4][p=128][16B] over dense p = bI*CW + l
__global__ __launch_bounds__(256) void transpose_x(const float* __restrict__ src,
                                                   float* __restrict__ dst,
                                                   unsigned short* __restrict__ Ximg) {
  __shared__ float sT[64][65];
  int l0 = blockIdx.x * 64, c0 = blockIdx.y * 64, bI = blockIdx.z;
  int tid = threadIdx.x;
  for (int i = tid; i < 4096; i += 256) {
    int ll = i & 63, cc = i >> 6;
    int l = l0 + ll;
    sT[cc][ll] = (l < CW) ? src[((size_t)bI * CC + c0 + cc) * CW + l] : 0.f;
  }
  __syncthreads();
  for (int i = tid; i < 4096; i += 256) {
    int cc = i & 63, ll = i >> 6;
    int l = l0 + ll;
    if (l < CW) dst[((size_t)bI * CW + l) * CC + c0 + cc] = sT[cc][ll];
  }
  uint4v* img4 = (uint4v*)Ximg;
  for (int i = tid; i < 512; i += 256) {
    int ch8 = i & 7, ll = i >> 3;
    int l = l0 + ll;
    if (l >= CW) continue;
    unsigned short h[8];
#pragma unroll
    for (int j = 0; j < 8; j++) h[j] = f2bf(sT[ch8 * 8 + j][ll]);
    uint4v v;
    v[0] = (unsigned)h[0] | ((unsigned)h[1] << 16);
    v[1] = (unsigned)h[2] | ((unsigned)h[3] << 16);
    v[2] = (unsigned)h[4] | ((unsigned)h[5] << 16);
    v[3] = (unsigned)h[6] | ((unsigned)h[7] << 16);
    int cb = c0 + ch8 * 8;
    int p = bI * CW + l;
    int ptile = p >> 7, pp = p & 127;
    int ktile = cb >> 5, kchunk = (cb >> 3) & 3;
    img4[((size_t)ptile * 8 + ktile) * 512 + kchunk * 128 + pp] = v;
  }
}

// All weight staging in one launch: Wimg0 (blk0 qkv), Wimg1 (blk1 qkv), Wimg2 (proj).
// Image: [otile][ktile=8][kchunk=4][o=128][16B]  (bf16, K=256)
__global__ __launch_bounds__(256) void prep_w_all(
    const float* __restrict__ qk_W, const float* __restrict__ v_W,
    const float* __restrict__ proj_W, unsigned short* __restrict__ Wimg0,
    unsigned short* __restrict__ Wimg1, unsigned short* __restrict__ Wimg2) {
  int t = blockIdx.x * 256 + threadIdx.x;
  if (t >= 2816 * 32) return;
  int og = t >> 5, ch = t & 31;
  const float* row;
  unsigned short* dstimg;
  int o;
  if (og < 1280) {
    o = og;
    row = (o < 1024) ? (qk_W + (size_t)o * CC) : (v_W + (size_t)(o - 1024) * CC);
    dstimg = Wimg0;
  } else if (og < 2560) {
    o = og - 1280;
    row = (o < 1024) ? (qk_W + (size_t)(1024 + o) * CC)
                     : (v_W + (size_t)(256 + o - 1024) * CC);
    dstimg = Wimg1;
  } else {
    o = og - 2560;
    row = proj_W + (size_t)o * CC;
    dstimg = Wimg2;
  }
  unsigned short h[8];
#pragma unroll
  for (int j = 0; j < 8; j++) h[j] = f2bf(row[ch * 8 + j]);
  uint4v v;
  v[0] = (unsigned)h[0] | ((unsigned)h[1] << 16);
  v[1] = (unsigned)h[2] | ((unsigned)h[3] << 16);
  v[2] = (unsigned)h[4] | ((unsigned)h[5] << 16);
  v[3] = (unsigned)h[6] | ((unsigned)h[7] << 16);
  int otile = o >> 7, oo = o & 127;
  int ktile = ch >> 2, kchunk = ch & 3;
  uint4v* img4 = (uint4v*)dstimg;
  img4[((size_t)otile * 8 + ktile) * 512 + kchunk * 128 + oo] = v;
}

// x staging (bf16, K=256): [ptile][ktile=8][kchunk=4][p=128][16B], from xcur rows
__global__ __launch_bounds__(256) void prep_x(const float* __restrict__ X,
                                              unsigned short* __restrict__ img, int P) {
  int ptile = blockIdx.x, cq = blockIdx.y;
  int c0 = cq * 64;
  __shared__ float sX[64][129];
  int tid = threadIdx.x;
  for (int i = tid; i < 64 * 128; i += 256) {
    int cc = i & 63, pp = i >> 6;
    int p = ptile * 128 + pp;
    sX[cc][pp] = (p < P) ? X[(size_t)p * CC + c0 + cc] : 0.f;
  }
  __syncthreads();
  uint4v* img4 = (uint4v*)img;
  for (int i = tid; i < 1024; i += 256) {
    int ch = i >> 7, pp = i & 127;
    unsigned short h[8];
#pragma unroll
    for (int j = 0; j < 8; j++) h[j] = f2bf(sX[ch * 8 + j][pp]);
    uint4v vh;
    vh[0] = (unsigned)h[0] | ((unsigned)h[1] << 16);
    vh[1] = (unsigned)h[2] | ((unsigned)h[3] << 16);
    vh[2] = (unsigned)h[4] | ((unsigned)h[5] << 16);
    vh[3] = (unsigned)h[6] | ((unsigned)h[7] << 16);
    int ktile = cq * 2 + (ch >> 2), kchunk = ch & 3;
    img4[((size_t)ptile * 8 + ktile) * 512 + kchunk * 128 + pp] = vh;
  }
}

// Fused qkv GEMM, K=256, global->reg fragments, XCD-group swizzle.
// Trailing blocks (raw >= gemmBlocks) do pad-fill for l in [CW,L) concurrently.
__global__ __launch_bounds__(256, 3) void gemm_qkv(
    const unsigned short* __restrict__ Aimg, const unsigned short* __restrict__ Ximg,
    const float* __restrict__ G0, const float* __restrict__ B0,
    const float* __restrict__ M0, const float* __restrict__ V0,
    const float* __restrict__ G1, const float* __restrict__ B1,
    const float* __restrict__ M1, const float* __restrict__ V1,
    unsigned short* __restrict__ qimg, unsigned short* __restrict__ kimg,
    float* __restrict__ v0pm, int L, int P, int nOt, int ptiles, int gemmBlocks) {
  int raw = blockIdx.x;
  int tid = threadIdx.x;
  if (raw >= gemmBlocks) {
    // pad-fill path: one block per pad row
    int pidx = raw - gemmBlocks;
    int nPad = L - CW;
    int bI = pidx / nPad, l = CW + (pidx - bI * nPad);
    for (int o = tid; o < 1280; o += 256) {
      if (o < 1024) {
        float s = G0[o] * rsqrtf(V0[o] + 1e-5f);
        float sh = B0[o] - M0[o] * s;
        int nh = o >> 7, sp = (o >> 6) & 1, d = o & 63;
        unsigned short* dst = sp ? kimg : qimg;
        dst[(((size_t)(bI * NHh + nh)) * L + l) * QROW + d] = f2bf(sp ? sh : sh * 0.125f);
      } else {
        int oc = o - 1024;
        float s = G1[oc] * rsqrtf(V1[oc] + 1e-5f);
        float sh = B1[oc] - M1[oc] * s;
        v0pm[((size_t)bI * L + l) * VROW + oc] = sh;
      }
    }
    return;
  }
  int xcd = raw & 7;
  int t = raw >> 3;
  int ptile = (t / nOt) * 8 + xcd;
  int otile = t % nOt;
  if (ptile >= ptiles) return;
  int wid = tid >> 6, lane = tid & 63;
  int wr = wid >> 1, wc = wid & 1;
  int r = lane & 15, kb = lane >> 4;
  bool isV = otile >= 8;
  f32x4 acc[4][4] = {};
  const unsigned short* Ap = Aimg + (size_t)otile * 32768 + kb * 1024 + (wr * 64 + r) * 8;
  const unsigned short* Bp = Ximg + (size_t)ptile * 32768 + kb * 1024 + (wc * 64 + r) * 8;
#pragma unroll
  for (int kt = 0; kt < 8; kt++) {
    short8 a[4], b[4];
#pragma unroll
    for (int mi = 0; mi < 4; mi++) a[mi] = *(const short8*)(Ap + kt * 4096 + mi * 128);
#pragma unroll
    for (int ni = 0; ni < 4; ni++) b[ni] = *(const short8*)(Bp + kt * 4096 + ni * 128);
    if (!isV) {
#pragma unroll
      for (int mi = 0; mi < 4; mi++)
#pragma unroll
        for (int ni = 0; ni < 4; ni++)
          acc[mi][ni] = __builtin_amdgcn_mfma_f32_16x16x32_bf16(a[mi], b[ni], acc[mi][ni], 0, 0, 0);
    } else {
#pragma unroll
      for (int mi = 0; mi < 4; mi++)
#pragma unroll
        for (int ni = 0; ni < 4; ni++)
          acc[ni][mi] = __builtin_amdgcn_mfma_f32_16x16x32_bf16(b[ni], a[mi], acc[ni][mi], 0, 0, 0);
    }
  }
  int cl = lane & 15, r4 = lane >> 4;
  int p0 = ptile * 128;
  int bI0 = p0 / CW;
  int rem0 = p0 - bI0 * CW;
  if (!isV) {
#pragma unroll
    for (int mi = 0; mi < 4; mi++) {
      int obase = otile * 128 + wr * 64 + mi * 16 + r4 * 4;
      int sp = (obase >> 6) & 1;
      float qs = sp ? 1.f : 0.125f;
      float s4[4], sh4[4];
#pragma unroll
      for (int reg = 0; reg < 4; reg++) {
        int o = obase + reg;
        float sb = G0[o] * rsqrtf(V0[o] + 1e-5f);
        s4[reg] = sb * qs;
        sh4[reg] = (B0[o] - M0[o] * sb) * qs;
      }
      int nh = obase >> 7, d0 = obase & 63;
      unsigned short* dst = sp ? kimg : qimg;
#pragma unroll
      for (int ni = 0; ni < 4; ni++) {
        int off = wc * 64 + ni * 16 + cl;
        int p = p0 + off;
        if (p >= P) continue;
        int l = rem0 + off, bI = bI0;
        if (l >= CW) { l -= CW; bI++; }
        unsigned short hi[4];
#pragma unroll
        for (int reg = 0; reg < 4; reg++)
          hi[reg] = f2bf(acc[mi][ni][reg] * s4[reg] + sh4[reg]);
        uint2v hv;
        hv[0] = (unsigned)hi[0] | ((unsigned)hi[1] << 16);
        hv[1] = (unsigned)hi[2] | ((unsigned)hi[3] << 16);
        *(uint2v*)(dst + (((size_t)(bI * NHh + nh)) * L + l) * QROW + d0) = hv;
      }
    }
  } else {
#pragma unroll
    for (int mi = 0; mi < 4; mi++) {
      int oc = (otile - 8) * 128 + wr * 64 + mi * 16 + cl;
      float s = G1[oc] * rsqrtf(V1[oc] + 1e-5f);
      float sh = B1[oc] - M1[oc] * s;
#pragma unroll
      for (int ni = 0; ni < 4; ni++) {
#pragma unroll
        for (int reg = 0; reg < 4; reg++) {
          int off = wc * 64 + ni * 16 + r4 * 4 + reg;
          int p = p0 + off;
          if (p >= P) continue;
          int l = rem0 + off, bI = bI0;
          if (l >= CW) { l -= CW; bI++; }
          v0pm[((size_t)bI * L + l) * VROW + oc] = acc[ni][mi][reg] * s + sh;
        }
      }
    }
  }
}

// proj GEMM: K=256, 64-wide p tiles; out (b,256,CW) fp32
__global__ __launch_bounds__(256, 3) void gemm_proj(
    const unsigned short* __restrict__ Aimg, const unsigned short* __restrict__ Ximg,
    const float* __restrict__ G0, const float* __restrict__ B0,
    const float* __restrict__ M0, const float* __restrict__ V0,
    float* __restrict__ out, int P, int nOt, int ptiles64) {
  int raw = blockIdx.x;
  int xcd = raw & 7;
  int t = raw >> 3;
  int p64 = (t / nOt) * 8 + xcd;
  int otile = t % nOt;
  if (p64 >= ptiles64) return;
  int tid = threadIdx.x;
  int wid = tid >> 6, lane = tid & 63;
  int wr = wid >> 1, wc = wid & 1;
  int r = lane & 15, kb = lane >> 4;
  f32x4 acc[4][2] = {};
  int ptile128 = p64 >> 1;
  int psub = (p64 & 1) * 64;
  const unsigned short* Ap = Aimg + (size_t)otile * 32768 + kb * 1024 + (wr * 64 + r) * 8;
  const unsigned short* Bp = Ximg + (size_t)ptile128 * 32768 + kb * 1024 + (psub + wc * 32 + r) * 8;
#pragma unroll
  for (int kt = 0; kt < 8; kt++) {
    short8 a[4], b[2];
#pragma unroll
    for (int mi = 0; mi < 4; mi++) a[mi] = *(const short8*)(Ap + kt * 4096 + mi * 128);
#pragma unroll
    for (int ni = 0; ni < 2; ni++) b[ni] = *(const short8*)(Bp + kt * 4096 + ni * 128);
#pragma unroll
    for (int mi = 0; mi < 4; mi++)
#pragma unroll
      for (int ni = 0; ni < 2; ni++)
        acc[mi][ni] = __builtin_amdgcn_mfma_f32_16x16x32_bf16(a[mi], b[ni], acc[mi][ni], 0, 0, 0);
  }
  int cl = lane & 15, r4 = lane >> 4;
  int p0 = p64 * 64;
  int bI0 = p0 / CW;
  int rem0 = p0 - bI0 * CW;
#pragma unroll
  for (int mi = 0; mi < 4; mi++) {
#pragma unroll
    for (int reg = 0; reg < 4; reg++) {
      int o = otile * 128 + wr * 64 + mi * 16 + r4 * 4 + reg;
      float s = G0[o] * rsqrtf(V0[o] + 1e-5f);
      float sh = B0[o] - M0[o] * s;
#pragma unroll
      for (int ni = 0; ni < 2; ni++) {
        int off = wc * 32 + ni * 16 + cl;
        int p = p0 + off;
        if (p >= P) continue;
        int l = rem0 + off, bI = bI0;
        if (l >= CW) { l -= CW; bI++; }
        out[((size_t)bI * CC + o) * CW + l] = acc[mi][ni][reg] * s + sh;
      }
    }
  }
}

// MFMA-gram fused attention level-PAIR. One wave per B*B block.
// v path vectorized: lane = (channel-pair 0-15)*2 x (slot 0-3), f32x2 accesses.
template <int B, bool DO_A, bool DO_B>
__global__ __launch_bounds__(256) void attn_mfma(
    const unsigned short* __restrict__ qimg, const unsigned short* __restrict__ kimg,
    const float* __restrict__ vin, float* __restrict__ vout,
    int L, int s2, int bpb) {
  constexpr int B2 = B * B;
  constexpr int MT = (B2 + 15) / 16;
  __shared__ float S[4][256];
  int tid = threadIdx.x;
  int w = tid >> 6, lane = tid & 63;
  int gid = blockIdx.x * 4 + w;
  int bh = gid / bpb;
  int g = gid - bh * bpb;
  int hi_ = g / s2, lo_ = g - hi_ * s2;
  int base0 = hi_ * B2 * s2 + lo_;
  int cl = lane & 15, r4 = lane >> 4;
  int c2 = (lane & 15) * 2, slot4 = lane >> 4;
  int bI = bh >> 3, nh = bh & 7;

  short8 kh[MT][2], qh[MT][2];
#pragma unroll
  for (int mt = 0; mt < MT; mt++) {
    int idx = mt * 16 + cl;
    if (idx > B2 - 1) idx = B2 - 1;
    size_t row = ((size_t)bh * L + base0 + idx * s2) * QROW;
#pragma unroll
    for (int kt = 0; kt < 2; kt++) {
      int dof = kt * 32 + r4 * 8;
      kh[mt][kt] = *(const short8*)(kimg + row + dof);
      qh[mt][kt] = *(const short8*)(qimg + row + dof);
    }
  }
  size_t vBase = ((size_t)bI * L + base0) * VROW + nh * HDd + c2;
  f32x2 vv[B2];
#pragma unroll
  for (int idx = 0; idx < B2; idx++)
    vv[idx] = *(const f32x2*)(vin + vBase + (size_t)(idx * s2) * VROW);

  f32x4 C[MT][MT] = {};
#pragma unroll
  for (int kt = 0; kt < 2; kt++)
#pragma unroll
    for (int mt = 0; mt < MT; mt++)
#pragma unroll
      for (int nt = 0; nt < MT; nt++)
        C[mt][nt] = __builtin_amdgcn_mfma_f32_16x16x32_bf16(kh[mt][kt], qh[nt][kt], C[mt][nt], 0, 0, 0);
#pragma unroll
  for (int mt = 0; mt < MT; mt++)
#pragma unroll
    for (int nt = 0; nt < MT; nt++)
#pragma unroll
      for (int rr = 0; rr < 4; rr++) {
        int J_idx = mt * 16 + r4 * 4 + rr;
        int j_idx = nt * 16 + cl;
        if (J_idx < B2 && j_idx < B2) {
          float val = C[mt][nt][rr];
          int Jq, bJ, jq, bj;
          if (B == 4) {
            Jq = J_idx >> 2; bJ = J_idx & 3; jq = j_idx >> 2; bj = j_idx & 3;
          } else {
            Jq = (J_idx * 205) >> 10; bJ = J_idx - Jq * 5;
            jq = (j_idx * 205) >> 10; bj = j_idx - jq * 5;
          }
          if (DO_A && bJ == bj) S[w][(bJ * B + Jq) * B + jq] = val;
          if (DO_B && Jq == jq) S[w][128 + (Jq * B + bJ) * B + bj] = val;
        }
      }
  if (DO_A) {
#pragma unroll
    for (int b = 0; b < B; b++) {
      f32x2 tmp[B];
#pragma unroll
      for (int J = 0; J < B; J++) {
        float sc[B];
#pragma unroll
        for (int j = 0; j < B; j++) sc[j] = S[w][(b * B + J) * B + j];
        float mx = sc[0];
#pragma unroll
        for (int j = 1; j < B; j++) mx = fmaxf(mx, sc[j]);
        float sum = 0.f;
        f32x2 acc = {0.f, 0.f};
#pragma unroll
        for (int j = 0; j < B; j++) {
          float e = __expf(sc[j] - mx);
          sum += e;
          acc += vv[j * B + b] * e;
        }
        float inv = 1.f / sum;
        tmp[J] = acc * inv;
      }
#pragma unroll
      for (int J = 0; J < B; J++) vv[J * B + b] = tmp[J];
    }
  }
  if (DO_B) {
#pragma unroll
    for (int a = 0; a < B; a++) {
      f32x2 tmp[B];
#pragma unroll
      for (int J = 0; J < B; J++) {
        float sc[B];
#pragma unroll
        for (int j = 0; j < B; j++) sc[j] = S[w][128 + (a * B + J) * B + j];
        float mx = sc[0];
#pragma unroll
        for (int j = 1; j < B; j++) mx = fmaxf(mx, sc[j]);
        float sum = 0.f;
        f32x2 acc = {0.f, 0.f};
#pragma unroll
        for (int j = 0; j < B; j++) {
          float e = __expf(sc[j] - mx);
          sum += e;
          acc += vv[a * B + j] * e;
        }
        float inv = 1.f / sum;
        tmp[J] = acc * inv;
      }
#pragma unroll
      for (int J = 0; J < B; J++) vv[a * B + J] = tmp[J];
    }
  }
#pragma unroll
  for (int idx = 0; idx < B2; idx++)
    if ((idx & 3) == slot4)
      *(f32x2*)(vout + vBase + (size_t)(idx * s2) * VROW) = vv[idx];
}

// TRI-level fused attention (r13/r15 structure; float4 v path).
// One 256-thread workgroup per B^3 block. sv stride 36 floats (16B-aligned quads).
// FUSE (S==1 final pass): xcur += v + BN(dwconv3(v0pm)), float4 per 4 channels.
template <int B, int S, bool FUSE>
__global__ __launch_bounds__(256) void attn_tri(
    const unsigned short* __restrict__ qimg, const unsigned short* __restrict__ kimg,
    const float* __restrict__ vin, float* __restrict__ vout,
    int L, int nblk,
    const float* __restrict__ peW, const float* __restrict__ Gp,
    const float* __restrict__ Bp2, const float* __restrict__ Mp,
    const float* __restrict__ Vp, const float* __restrict__ v0pm,
    float* __restrict__ xcur) {
  constexpr int B2 = B * B;
  constexpr int B3 = B * B * B;
  constexpr int NT = (B3 + 15) / 16;
  constexpr int MTW = (NT + 3) / 4;
  constexpr int SVS = 36;  // sv row stride (floats), 16B-aligned quads, non-pow2 banks
  __shared__ float slab[3 * B2 * B * B];
  __shared__ float sv[B3 * SVS];
  int tid = threadIdx.x;
  int w = tid >> 6, lane = tid & 63;
  int bid = blockIdx.x;
  int bh = bid / nblk;
  int blk = bid - bh * nblk;
  int hi = blk / S, lo = blk - hi * S;
  int base0 = hi * B3 * S + lo;
  int bI = bh >> 3, nh = bh & 7;
  int cl = lane & 15, r4 = lane >> 4;

  // v -> LDS, float4 (4 channels per thread)
  for (int t = tid; t < B3 * 8; t += 256) {
    int cq = t & 7, idx = t >> 3;
    *(f32x4*)(&sv[idx * SVS + cq * 4]) = *(const f32x4*)(
        vin + ((size_t)bI * L + base0 + idx * S) * VROW + nh * HDd + cq * 4);
  }

  short8 kh[MTW][2], qh[NT][2];
#pragma unroll
  for (int m = 0; m < MTW; m++) {
    int idx = (w * MTW + m) * 16 + cl;
    if (idx > B3 - 1) idx = B3 - 1;
    size_t row = ((size_t)bh * L + base0 + idx * S) * QROW;
#pragma unroll
    for (int kt = 0; kt < 2; kt++)
      kh[m][kt] = *(const short8*)(kimg + row + kt * 32 + r4 * 8);
  }
#pragma unroll
  for (int nt = 0; nt < NT; nt++) {
    int idx = nt * 16 + cl;
    if (idx > B3 - 1) idx = B3 - 1;
    size_t row = ((size_t)bh * L + base0 + idx * S) * QROW;
#pragma unroll
    for (int kt = 0; kt < 2; kt++)
      qh[nt][kt] = *(const short8*)(qimg + row + kt * 32 + r4 * 8);
  }
  f32x4 C[MTW][NT] = {};
#pragma unroll
  for (int kt = 0; kt < 2; kt++)
#pragma unroll
    for (int m = 0; m < MTW; m++)
#pragma unroll
      for (int nt = 0; nt < NT; nt++)
        C[m][nt] = __builtin_amdgcn_mfma_f32_16x16x32_bf16(kh[m][kt], qh[nt][kt], C[m][nt], 0, 0, 0);
#pragma unroll
  for (int m = 0; m < MTW; m++)
#pragma unroll
    for (int nt = 0; nt < NT; nt++)
#pragma unroll
      for (int rr = 0; rr < 4; rr++) {
        int J = (w * MTW + m) * 16 + r4 * 4 + rr;
        int j = nt * 16 + cl;
        if (J < B3 && j < B3) {
          float val = C[m][nt][rr];
          int A2 = J / B2, Jr = J - A2 * B2, A1 = Jr / B, A0 = Jr - A1 * B;
          int a2 = j / B2, jr = j - a2 * B2, a1 = jr / B, a0 = jr - a1 * B;
          if (A1 == a1 && A0 == a0) slab[((0 * B2 + (a1 * B + a0)) * B + A2) * B + a2] = val;
          if (A2 == a2 && A0 == a0) slab[((1 * B2 + (a2 * B + a0)) * B + A1) * B + a1] = val;
          if (A2 == a2 && A1 == a1) slab[((2 * B2 + (a2 * B + a1)) * B + A0) * B + a0] = val;
        }
      }
  __syncthreads();
  if (tid < 3 * B2) {
    float* bw = &slab[tid * B * B];
#pragma unroll
    for (int J = 0; J < B; J++) {
      float mx = bw[J * B];
#pragma unroll
      for (int j = 1; j < B; j++) mx = fmaxf(mx, bw[J * B + j]);
      float sum = 0.f;
      float e[B];
#pragma unroll
      for (int j = 0; j < B; j++) {
        e[j] = __expf(bw[J * B + j] - mx);
        sum += e[j];
      }
      float inv = 1.f / sum;
#pragma unroll
      for (int j = 0; j < B; j++) bw[J * B + j] = e[j] * inv;
    }
  }
  __syncthreads();
  int c = tid & 31, slot = tid >> 5;
  for (int lvl = 0; lvl < 3; lvl++) {
    for (int g = slot; g < B2; g += 8) {
      int ghi = g / B, glo = g - ghi * B;
      const float* wrow = &slab[(lvl * B2 + g) * B * B];
      float vvals[B], outs[B];
#pragma unroll
      for (int j = 0; j < B; j++) {
        int pid = (lvl == 0) ? (j * B2 + g) : (lvl == 1) ? (ghi * B2 + j * B + glo) : (g * B + j);
        vvals[j] = sv[pid * SVS + c];
      }
#pragma unroll
      for (int J = 0; J < B; J++) {
        float a = 0.f;
#pragma unroll
        for (int j = 0; j < B; j++) a += wrow[J * B + j] * vvals[j];
        outs[J] = a;
      }
#pragma unroll
      for (int J = 0; J < B; J++) {
        int pid = (lvl == 0) ? (J * B2 + g) : (lvl == 1) ? (ghi * B2 + J * B + glo) : (g * B + J);
        sv[pid * SVS + c] = outs[J];
      }
    }
    __syncthreads();
  }
  if (!FUSE) {
    for (int t = tid; t < B3 * 8; t += 256) {
      int cq = t & 7, idx = t >> 3;
      *(f32x4*)(vout + ((size_t)bI * L + base0 + idx * S) * VROW + nh * HDd + cq * 4) =
          *(const f32x4*)(&sv[idx * SVS + cq * 4]);
    }
  } else {
    int cq = tid & 7, slot2 = tid >> 3;
    int ch0 = nh * HDd + cq * 4;
    float pw0[4], pw1[4], pw2[4], ss[4], sh[4];
#pragma unroll
    for (int j = 0; j < 4; j++) {
      int ch = ch0 + j;
      pw0[j] = peW[ch * 3 + 0];
      pw1[j] = peW[ch * 3 + 1];
      pw2[j] = peW[ch * 3 + 2];
      ss[j] = Gp[ch] * rsqrtf(Vp[ch] + 1e-5f);
      sh[j] = Bp2[ch] - Mp[ch] * ss[j];
    }
    for (int idx = slot2; idx < B3; idx += 32) {
      int l = base0 + idx;  // S == 1 in FUSE passes
      if (l >= CW) continue;
      size_t row = ((size_t)bI * L + l) * VROW + ch0;
      f32x4 mid = *(const f32x4*)(v0pm + row);
      f32x4 left = {0.f, 0.f, 0.f, 0.f}, right = {0.f, 0.f, 0.f, 0.f};
      if (l > 0) left = *(const f32x4*)(v0pm + row - VROW);
      if (l + 1 < L) right = *(const f32x4*)(v0pm + row + VROW);
      float* xp = xcur + ((size_t)bI * CW + l) * CC + ch0;
      f32x4 x4 = *(f32x4*)xp;
#pragma unroll
      for (int j = 0; j < 4; j++) {
        float pe = (left[j] * pw0[j] + mid[j] * pw1[j] + right[j] * pw2[j]) * ss[j] + sh[j];
        x4[j] += sv[idx * SVS + cq * 4 + j] + pe;
      }
      *(f32x4*)xp = x4;
    }
  }
}

extern "C" void kernel_launch(void* const* d_in, const int* in_sizes, int n_in,
                              void* d_out, int out_size, void* d_ws, size_t ws_size,
                              hipStream_t stream) {
  const float* x = (const float*)d_in[0];
  const float* qk_W = (const float*)d_in[1];
  const float* qk_g = (const float*)d_in[2];
  const float* qk_b = (const float*)d_in[3];
  const float* qk_m = (const float*)d_in[4];
  const float* qk_v = (const float*)d_in[5];
  const float* v_W = (const float*)d_in[6];
  const float* v_g = (const float*)d_in[7];
  const float* v_b = (const float*)d_in[8];
  const float* v_m = (const float*)d_in[9];
  const float* v_v = (const float*)d_in[10];
  const float* pe_W = (const float*)d_in[11];
  const float* pe_g = (const float*)d_in[12];
  const float* pe_b = (const float*)d_in[13];
  const float* pe_m = (const float*)d_in[14];
  const float* pe_v = (const float*)d_in[15];
  const float* proj_W = (const float*)d_in[16];
  const float* proj_g = (const float*)d_in[17];
  const float* proj_b = (const float*)d_in[18];
  const float* proj_m = (const float*)d_in[19];
  const float* proj_v = (const float*)d_in[20];

  char* ws = (char*)d_ws;
  size_t off = 0;
  auto alloc = [&](size_t bytes) {
    char* p = ws + off;
    off += (bytes + 255) & ~(size_t)255;
    return (void*)p;
  };
  const int Lmax = 4096;
  const int P = CB * CW;
  const int ptiles = (P + 127) / 128;      // 98
  float* xcur = (float*)alloc((size_t)CB * CW * CC * 4);
  unsigned short* qimg = (unsigned short*)alloc((size_t)CB * NHh * Lmax * QROW * 2);
  unsigned short* kimg = (unsigned short*)alloc((size_t)CB * NHh * Lmax * QROW * 2);
  float* v0pm = (float*)alloc((size_t)CB * Lmax * VROW * 4);
  float* vA = (float*)alloc((size_t)CB * Lmax * VROW * 4);
  unsigned short* Ximg = (unsigned short*)alloc((size_t)ptiles * 32768 * 2);  // 6.4 MB
  unsigned short* Wimg0 = (unsigned short*)alloc((size_t)10 * 8 * 8192 * 2);
  unsigned short* Wimg1 = (unsigned short*)alloc((size_t)10 * 8 * 8192 * 2);
  unsigned short* Wimg2 = (unsigned short*)alloc((size_t)2 * 8 * 8192 * 2);
  (void)ws_size;

  // all weight staging in one launch
  prep_w_all<<<(2816 * 32 + 255) / 256, 256, 0, stream>>>(qk_W, v_W, proj_W,
                                                          Wimg0, Wimg1, Wimg2);
  // transpose + direct Ximg emit (replaces prep_x #1)
  {
    dim3 gt((CW + 63) / 64, 4, CB);
    transpose_x<<<gt, 256, 0, stream>>>(x, xcur, Ximg);
  }

  const int pgroups8 = (ptiles + 7) / 8;   // 13
  const int ptiles64 = (P + 63) / 64;      // 196
  const int pg64 = (ptiles64 + 7) / 8;     // 25
  const int gemmBlocks = 8 * pgroups8 * 10;
  const int Ls[2] = {3125, 4096};
  const unsigned short* Wimgs[2] = {Wimg0, Wimg1};
  for (int blk = 0; blk < 2; blk++) {
    int L = Ls[blk];
    if (blk == 1) {
      dim3 gx(ptiles, 4);
      prep_x<<<gx, 256, 0, stream>>>(xcur, Ximg, P);
    }
    int padBlocks = (L > CW) ? CB * (L - CW) : 0;
    gemm_qkv<<<gemmBlocks + padBlocks, 256, 0, stream>>>(
        Wimgs[blk], Ximg, qk_g + blk * 1024, qk_b + blk * 1024, qk_m + blk * 1024,
        qk_v + blk * 1024, v_g + blk * CC, v_b + blk * CC, v_m + blk * CC,
        v_v + blk * CC, qimg, kimg, v0pm, L, P, 10, ptiles, gemmBlocks);

    const float* peWb = pe_W + (size_t)blk * CC * 3;
    const float* peG = pe_g + blk * CC;
    const float* peB = pe_b + blk * CC;
    const float* peM = pe_m + blk * CC;
    const float* peV = pe_v + blk * CC;
    if (blk == 0) {
      // base 5: levels 0,1 (pair, s2=125) then levels 2,3,4 (tri, S=1) + FUSE
      int bpb = L / 25;  // 125
      attn_mfma<5, true, true><<<(CB * NHh * bpb) / 4, 256, 0, stream>>>(
          qimg, kimg, v0pm, vA, L, 125, bpb);
      int nblk = L / 125;  // 25
      attn_tri<5, 1, true><<<CB * NHh * nblk, 256, 0, stream>>>(
          qimg, kimg, vA, nullptr, L, nblk, peWb, peG, peB, peM, peV, v0pm, xcur);
    } else {
      // base 4: levels 0,1,2 (tri, S=64) then levels 3,4,5 (tri, S=1) + FUSE
      int nblk = L / 64;  // 64
      attn_tri<4, 64, false><<<CB * NHh * nblk, 256, 0, stream>>>(
          qimg, kimg, v0pm, vA, L, nblk, nullptr, nullptr, nullptr, nullptr,
          nullptr, nullptr, nullptr);
      attn_tri<4, 1, true><<<CB * NHh * nblk, 256, 0, stream>>>(
          qimg, kimg, vA, nullptr, L, nblk, peWb, peG, peB, peM, peV, v0pm, xcur);
    }
  }
  {
    dim3 gx(ptiles, 4);
    prep_x<<<gx, 256, 0, stream>>>(xcur, Ximg, P);
    gemm_proj<<<8 * pg64 * 2, 256, 0, stream>>>(
        Wimg2, Ximg, proj_g, proj_b, proj_m, proj_v, (float*)d_out, P, 2, ptiles64);
  }
}

// Round 22
// 235.874 us; speedup vs baseline: 1.0115x; 1.0115x over previous
//
#include <hip/hip_runtime.h>
#include <math.h>

constexpr int CW = 3125;   // valid width
constexpr int CC = 256;    // channels
constexpr int CB = 4;      // batch
constexpr int NHh = 8;     // heads
constexpr int KDd = 64;    // qk head dim
constexpr int HDd = 32;    // v head dim
constexpr int QROW = 64;   // q/k image row stride in shorts
constexpr int VROW = 256;  // v buffer row stride in floats

typedef __attribute__((ext_vector_type(8))) short short8;
typedef __attribute__((ext_vector_type(4))) float f32x4;
typedef __attribute__((ext_vector_type(4))) unsigned int uint4v;
typedef __attribute__((ext_vector_type(2))) unsigned int uint2v;

__device__ inline unsigned short f2bf(float x) {
  unsigned int u = __float_as_uint(x);
  unsigned int r = u + 0x7FFFu + ((u >> 16) & 1u);
  return (unsigned short)(r >> 16);
}

// x (b,256,CW) -> xcur (b,CW,256) position-major AND Ximg staged bf16 image
// Ximg: [ptile][ktile=8][kchunk=4][p=128][16B] over dense p = bI*CW + l
__global__ __launch_bounds__(256) void transpose_x(const float* __restrict__ src,
                                                   float* __restrict__ dst,
                                                   unsigned short* __restrict__ Ximg) {
  __shared__ float sT[64][65];
  int l0 = blockIdx.x * 64, c0 = blockIdx.y * 64, bI = blockIdx.z;
  int tid = threadIdx.x;
  for (int i = tid; i < 4096; i += 256) {
    int ll = i & 63, cc = i >> 6;
    int l = l0 + ll;
    sT[cc][ll] = (l < CW) ? src[((size_t)bI * CC + c0 + cc) * CW + l] : 0.f;
  }
  __syncthreads();
  for (int i = tid; i < 4096; i += 256) {
    int cc = i & 63, ll = i >> 6;
    int l = l0 + ll;
    if (l < CW) dst[((size_t)bI * CW + l) * CC + c0 + cc] = sT[cc][ll];
  }
  uint4v* img4 = (uint4v*)Ximg;
  for (int i = tid; i < 512; i += 256) {
    int ch8 = i & 7, ll = i >> 3;
    int l = l0 + ll;
    if (l >= CW) continue;
    unsigned short h[8];
#pragma unroll
    for (int j = 0; j < 8; j++) h[j] = f2bf(sT[ch8 * 8 + j][ll]);
    uint4v v;
    v[0] = (unsigned)h[0] | ((unsigned)h[1] << 16);
    v[1] = (unsigned)h[2] | ((unsigned)h[3] << 16);
    v[2] = (unsigned)h[4] | ((unsigned)h[5] << 16);
    v[3] = (unsigned)h[6] | ((unsigned)h[7] << 16);
    int cb = c0 + ch8 * 8;
    int p = bI * CW + l;
    int ptile = p >> 7, pp = p & 127;
    int ktile = cb >> 5, kchunk = (cb >> 3) & 3;
    img4[((size_t)ptile * 8 + ktile) * 512 + kchunk * 128 + pp] = v;
  }
}

// All weight staging in one launch: Wimg0 (blk0 qkv), Wimg1 (blk1 qkv), Wimg2 (proj).
// Image: [otile][ktile=8][kchunk=4][o=128][16B]  (bf16, K=256)
__global__ __launch_bounds__(256) void prep_w_all(
    const float* __restrict__ qk_W, const float* __restrict__ v_W,
    const float* __restrict__ proj_W, unsigned short* __restrict__ Wimg0,
    unsigned short* __restrict__ Wimg1, unsigned short* __restrict__ Wimg2) {
  int t = blockIdx.x * 256 + threadIdx.x;
  if (t >= 2816 * 32) return;
  int og = t >> 5, ch = t & 31;
  const float* row;
  unsigned short* dstimg;
  int o;
  if (og < 1280) {
    o = og;
    row = (o < 1024) ? (qk_W + (size_t)o * CC) : (v_W + (size_t)(o - 1024) * CC);
    dstimg = Wimg0;
  } else if (og < 2560) {
    o = og - 1280;
    row = (o < 1024) ? (qk_W + (size_t)(1024 + o) * CC)
                     : (v_W + (size_t)(256 + o - 1024) * CC);
    dstimg = Wimg1;
  } else {
    o = og - 2560;
    row = proj_W + (size_t)o * CC;
    dstimg = Wimg2;
  }
  unsigned short h[8];
#pragma unroll
  for (int j = 0; j < 8; j++) h[j] = f2bf(row[ch * 8 + j]);
  uint4v v;
  v[0] = (unsigned)h[0] | ((unsigned)h[1] << 16);
  v[1] = (unsigned)h[2] | ((unsigned)h[3] << 16);
  v[2] = (unsigned)h[4] | ((unsigned)h[5] << 16);
  v[3] = (unsigned)h[6] | ((unsigned)h[7] << 16);
  int otile = o >> 7, oo = o & 127;
  int ktile = ch >> 2, kchunk = ch & 3;
  uint4v* img4 = (uint4v*)dstimg;
  img4[((size_t)otile * 8 + ktile) * 512 + kchunk * 128 + oo] = v;
}

// x staging (bf16, K=256): [ptile][ktile=8][kchunk=4][p=128][16B], from xcur rows
__global__ __launch_bounds__(256) void prep_x(const float* __restrict__ X,
                                              unsigned short* __restrict__ img, int P) {
  int ptile = blockIdx.x, cq = blockIdx.y;
  int c0 = cq * 64;
  __shared__ float sX[64][129];
  int tid = threadIdx.x;
  for (int i = tid; i < 64 * 128; i += 256) {
    int cc = i & 63, pp = i >> 6;
    int p = ptile * 128 + pp;
    sX[cc][pp] = (p < P) ? X[(size_t)p * CC + c0 + cc] : 0.f;
  }
  __syncthreads();
  uint4v* img4 = (uint4v*)img;
  for (int i = tid; i < 1024; i += 256) {
    int ch = i >> 7, pp = i & 127;
    unsigned short h[8];
#pragma unroll
    for (int j = 0; j < 8; j++) h[j] = f2bf(sX[ch * 8 + j][pp]);
    uint4v vh;
    vh[0] = (unsigned)h[0] | ((unsigned)h[1] << 16);
    vh[1] = (unsigned)h[2] | ((unsigned)h[3] << 16);
    vh[2] = (unsigned)h[4] | ((unsigned)h[5] << 16);
    vh[3] = (unsigned)h[6] | ((unsigned)h[7] << 16);
    int ktile = cq * 2 + (ch >> 2), kchunk = ch & 3;
    img4[((size_t)ptile * 8 + ktile) * 512 + kchunk * 128 + pp] = vh;
  }
}

// Fused qkv GEMM, K=256, global->reg fragments, XCD-group swizzle.
// Trailing blocks (raw >= gemmBlocks) do pad-fill for l in [CW,L) concurrently.
__global__ __launch_bounds__(256, 3) void gemm_qkv(
    const unsigned short* __restrict__ Aimg, const unsigned short* __restrict__ Ximg,
    const float* __restrict__ G0, const float* __restrict__ B0,
    const float* __restrict__ M0, const float* __restrict__ V0,
    const float* __restrict__ G1, const float* __restrict__ B1,
    const float* __restrict__ M1, const float* __restrict__ V1,
    unsigned short* __restrict__ qimg, unsigned short* __restrict__ kimg,
    float* __restrict__ v0pm, int L, int P, int nOt, int ptiles, int gemmBlocks) {
  int raw = blockIdx.x;
  int tid = threadIdx.x;
  if (raw >= gemmBlocks) {
    // pad-fill path: one block per pad row
    int pidx = raw - gemmBlocks;
    int nPad = L - CW;
    int bI = pidx / nPad, l = CW + (pidx - bI * nPad);
    for (int o = tid; o < 1280; o += 256) {
      if (o < 1024) {
        float s = G0[o] * rsqrtf(V0[o] + 1e-5f);
        float sh = B0[o] - M0[o] * s;
        int nh = o >> 7, sp = (o >> 6) & 1, d = o & 63;
        unsigned short* dst = sp ? kimg : qimg;
        dst[(((size_t)(bI * NHh + nh)) * L + l) * QROW + d] = f2bf(sp ? sh : sh * 0.125f);
      } else {
        int oc = o - 1024;
        float s = G1[oc] * rsqrtf(V1[oc] + 1e-5f);
        float sh = B1[oc] - M1[oc] * s;
        v0pm[((size_t)bI * L + l) * VROW + oc] = sh;
      }
    }
    return;
  }
  int xcd = raw & 7;
  int t = raw >> 3;
  int ptile = (t / nOt) * 8 + xcd;
  int otile = t % nOt;
  if (ptile >= ptiles) return;
  int wid = tid >> 6, lane = tid & 63;
  int wr = wid >> 1, wc = wid & 1;
  int r = lane & 15, kb = lane >> 4;
  bool isV = otile >= 8;
  f32x4 acc[4][4] = {};
  const unsigned short* Ap = Aimg + (size_t)otile * 32768 + kb * 1024 + (wr * 64 + r) * 8;
  const unsigned short* Bp = Ximg + (size_t)ptile * 32768 + kb * 1024 + (wc * 64 + r) * 8;
#pragma unroll
  for (int kt = 0; kt < 8; kt++) {
    short8 a[4], b[4];
#pragma unroll
    for (int mi = 0; mi < 4; mi++) a[mi] = *(const short8*)(Ap + kt * 4096 + mi * 128);
#pragma unroll
    for (int ni = 0; ni < 4; ni++) b[ni] = *(const short8*)(Bp + kt * 4096 + ni * 128);
    if (!isV) {
#pragma unroll
      for (int mi = 0; mi < 4; mi++)
#pragma unroll
        for (int ni = 0; ni < 4; ni++)
          acc[mi][ni] = __builtin_amdgcn_mfma_f32_16x16x32_bf16(a[mi], b[ni], acc[mi][ni], 0, 0, 0);
    } else {
#pragma unroll
      for (int mi = 0; mi < 4; mi++)
#pragma unroll
        for (int ni = 0; ni < 4; ni++)
          acc[ni][mi] = __builtin_amdgcn_mfma_f32_16x16x32_bf16(b[ni], a[mi], acc[ni][mi], 0, 0, 0);
    }
  }
  int cl = lane & 15, r4 = lane >> 4;
  int p0 = ptile * 128;
  int bI0 = p0 / CW;
  int rem0 = p0 - bI0 * CW;
  if (!isV) {
#pragma unroll
    for (int mi = 0; mi < 4; mi++) {
      int obase = otile * 128 + wr * 64 + mi * 16 + r4 * 4;
      int sp = (obase >> 6) & 1;
      float qs = sp ? 1.f : 0.125f;
      float s4[4], sh4[4];
#pragma unroll
      for (int reg = 0; reg < 4; reg++) {
        int o = obase + reg;
        float sb = G0[o] * rsqrtf(V0[o] + 1e-5f);
        s4[reg] = sb * qs;
        sh4[reg] = (B0[o] - M0[o] * sb) * qs;
      }
      int nh = obase >> 7, d0 = obase & 63;
      unsigned short* dst = sp ? kimg : qimg;
#pragma unroll
      for (int ni = 0; ni < 4; ni++) {
        int off = wc * 64 + ni * 16 + cl;
        int p = p0 + off;
        if (p >= P) continue;
        int l = rem0 + off, bI = bI0;
        if (l >= CW) { l -= CW; bI++; }
        unsigned short hi[4];
#pragma unroll
        for (int reg = 0; reg < 4; reg++)
          hi[reg] = f2bf(acc[mi][ni][reg] * s4[reg] + sh4[reg]);
        uint2v hv;
        hv[0] = (unsigned)hi[0] | ((unsigned)hi[1] << 16);
        hv[1] = (unsigned)hi[2] | ((unsigned)hi[3] << 16);
        *(uint2v*)(dst + (((size_t)(bI * NHh + nh)) * L + l) * QROW + d0) = hv;
      }
    }
  } else {
#pragma unroll
    for (int mi = 0; mi < 4; mi++) {
      int oc = (otile - 8) * 128 + wr * 64 + mi * 16 + cl;
      float s = G1[oc] * rsqrtf(V1[oc] + 1e-5f);
      float sh = B1[oc] - M1[oc] * s;
#pragma unroll
      for (int ni = 0; ni < 4; ni++) {
#pragma unroll
        for (int reg = 0; reg < 4; reg++) {
          int off = wc * 64 + ni * 16 + r4 * 4 + reg;
          int p = p0 + off;
          if (p >= P) continue;
          int l = rem0 + off, bI = bI0;
          if (l >= CW) { l -= CW; bI++; }
          v0pm[((size_t)bI * L + l) * VROW + oc] = acc[ni][mi][reg] * s + sh;
        }
      }
    }
  }
}

// proj GEMM: K=256, 64-wide p tiles; out (b,256,CW) fp32
__global__ __launch_bounds__(256, 3) void gemm_proj(
    const unsigned short* __restrict__ Aimg, const unsigned short* __restrict__ Ximg,
    const float* __restrict__ G0, const float* __restrict__ B0,
    const float* __restrict__ M0, const float* __restrict__ V0,
    float* __restrict__ out, int P, int nOt, int ptiles64) {
  int raw = blockIdx.x;
  int xcd = raw & 7;
  int t = raw >> 3;
  int p64 = (t / nOt) * 8 + xcd;
  int otile = t % nOt;
  if (p64 >= ptiles64) return;
  int tid = threadIdx.x;
  int wid = tid >> 6, lane = tid & 63;
  int wr = wid >> 1, wc = wid & 1;
  int r = lane & 15, kb = lane >> 4;
  f32x4 acc[4][2] = {};
  int ptile128 = p64 >> 1;
  int psub = (p64 & 1) * 64;
  const unsigned short* Ap = Aimg + (size_t)otile * 32768 + kb * 1024 + (wr * 64 + r) * 8;
  const unsigned short* Bp = Ximg + (size_t)ptile128 * 32768 + kb * 1024 + (psub + wc * 32 + r) * 8;
#pragma unroll
  for (int kt = 0; kt < 8; kt++) {
    short8 a[4], b[2];
#pragma unroll
    for (int mi = 0; mi < 4; mi++) a[mi] = *(const short8*)(Ap + kt * 4096 + mi * 128);
#pragma unroll
    for (int ni = 0; ni < 2; ni++) b[ni] = *(const short8*)(Bp + kt * 4096 + ni * 128);
#pragma unroll
    for (int mi = 0; mi < 4; mi++)
#pragma unroll
      for (int ni = 0; ni < 2; ni++)
        acc[mi][ni] = __builtin_amdgcn_mfma_f32_16x16x32_bf16(a[mi], b[ni], acc[mi][ni], 0, 0, 0);
  }
  int cl = lane & 15, r4 = lane >> 4;
  int p0 = p64 * 64;
  int bI0 = p0 / CW;
  int rem0 = p0 - bI0 * CW;
#pragma unroll
  for (int mi = 0; mi < 4; mi++) {
#pragma unroll
    for (int reg = 0; reg < 4; reg++) {
      int o = otile * 128 + wr * 64 + mi * 16 + r4 * 4 + reg;
      float s = G0[o] * rsqrtf(V0[o] + 1e-5f);
      float sh = B0[o] - M0[o] * s;
#pragma unroll
      for (int ni = 0; ni < 2; ni++) {
        int off = wc * 32 + ni * 16 + cl;
        int p = p0 + off;
        if (p >= P) continue;
        int l = rem0 + off, bI = bI0;
        if (l >= CW) { l -= CW; bI++; }
        out[((size_t)bI * CC + o) * CW + l] = acc[mi][ni][reg] * s + sh;
      }
    }
  }
}

// MFMA-gram fused attention level-PAIR (r9-proven). One wave per B*B block.
template <int B, bool DO_A, bool DO_B>
__global__ __launch_bounds__(256) void attn_mfma(
    const unsigned short* __restrict__ qimg, const unsigned short* __restrict__ kimg,
    const float* __restrict__ vin, float* __restrict__ vout,
    int L, int s2, int bpb) {
  constexpr int B2 = B * B;
  constexpr int MT = (B2 + 15) / 16;
  __shared__ float S[4][256];
  int tid = threadIdx.x;
  int w = tid >> 6, lane = tid & 63;
  int gid = blockIdx.x * 4 + w;
  int bh = gid / bpb;
  int g = gid - bh * bpb;
  int hi_ = g / s2, lo_ = g - hi_ * s2;
  int base0 = hi_ * B2 * s2 + lo_;
  int cl = lane & 15, r4 = lane >> 4;
  int dd = lane & 31, half = lane >> 5;
  int bI = bh >> 3, nh = bh & 7;

  short8 kh[MT][2], qh[MT][2];
#pragma unroll
  for (int mt = 0; mt < MT; mt++) {
    int idx = mt * 16 + cl;
    if (idx > B2 - 1) idx = B2 - 1;
    size_t row = ((size_t)bh * L + base0 + idx * s2) * QROW;
#pragma unroll
    for (int kt = 0; kt < 2; kt++) {
      int dof = kt * 32 + r4 * 8;
      kh[mt][kt] = *(const short8*)(kimg + row + dof);
      qh[mt][kt] = *(const short8*)(qimg + row + dof);
    }
  }
  size_t vBase = ((size_t)bI * L + base0) * VROW + nh * HDd + dd;
  float vv[B2];
#pragma unroll
  for (int idx = 0; idx < B2; idx++) vv[idx] = vin[vBase + (size_t)(idx * s2) * VROW];

  f32x4 C[MT][MT] = {};
#pragma unroll
  for (int kt = 0; kt < 2; kt++)
#pragma unroll
    for (int mt = 0; mt < MT; mt++)
#pragma unroll
      for (int nt = 0; nt < MT; nt++)
        C[mt][nt] = __builtin_amdgcn_mfma_f32_16x16x32_bf16(kh[mt][kt], qh[nt][kt], C[mt][nt], 0, 0, 0);
#pragma unroll
  for (int mt = 0; mt < MT; mt++)
#pragma unroll
    for (int nt = 0; nt < MT; nt++)
#pragma unroll
      for (int rr = 0; rr < 4; rr++) {
        int J_idx = mt * 16 + r4 * 4 + rr;
        int j_idx = nt * 16 + cl;
        if (J_idx < B2 && j_idx < B2) {
          float val = C[mt][nt][rr];
          int Jq, bJ, jq, bj;
          if (B == 4) {
            Jq = J_idx >> 2; bJ = J_idx & 3; jq = j_idx >> 2; bj = j_idx & 3;
          } else {
            Jq = (J_idx * 205) >> 10; bJ = J_idx - Jq * 5;
            jq = (j_idx * 205) >> 10; bj = j_idx - jq * 5;
          }
          if (DO_A && bJ == bj) S[w][(bJ * B + Jq) * B + jq] = val;
          if (DO_B && Jq == jq) S[w][128 + (Jq * B + bJ) * B + bj] = val;
        }
      }
  if (DO_A) {
#pragma unroll
    for (int b = 0; b < B; b++) {
      float tmp[B];
#pragma unroll
      for (int J = 0; J < B; J++) {
        float sc[B];
#pragma unroll
        for (int j = 0; j < B; j++) sc[j] = S[w][(b * B + J) * B + j];
        float mx = sc[0];
#pragma unroll
        for (int j = 1; j < B; j++) mx = fmaxf(mx, sc[j]);
        float sum = 0.f, acc = 0.f;
#pragma unroll
        for (int j = 0; j < B; j++) {
          float e = __expf(sc[j] - mx);
          sum += e;
          acc += e * vv[j * B + b];
        }
        tmp[J] = acc / sum;
      }
#pragma unroll
      for (int J = 0; J < B; J++) vv[J * B + b] = tmp[J];
    }
  }
  if (DO_B) {
#pragma unroll
    for (int a = 0; a < B; a++) {
      float tmp[B];
#pragma unroll
      for (int J = 0; J < B; J++) {
        float sc[B];
#pragma unroll
        for (int j = 0; j < B; j++) sc[j] = S[w][128 + (a * B + J) * B + j];
        float mx = sc[0];
#pragma unroll
        for (int j = 1; j < B; j++) mx = fmaxf(mx, sc[j]);
        float sum = 0.f, acc = 0.f;
#pragma unroll
        for (int j = 0; j < B; j++) {
          float e = __expf(sc[j] - mx);
          sum += e;
          acc += e * vv[a * B + j];
        }
        tmp[J] = acc / sum;
      }
#pragma unroll
      for (int J = 0; J < B; J++) vv[a * B + J] = tmp[J];
    }
  }
#pragma unroll
  for (int idx = 0; idx < B2; idx++)
    if ((idx & 1) == half) vout[vBase + (size_t)(idx * s2) * VROW] = vv[idx];
}

// TRI-level fused attention (r13/r15 structure; float4 v path).
// One 256-thread workgroup per B^3 block. sv stride 36 floats (16B-aligned quads).
// FUSE (S==1 final pass): xcur += v + BN(dwconv3(v0pm)), float4 per 4 channels.
template <int B, int S, bool FUSE>
__global__ __launch_bounds__(256) void attn_tri(
    const unsigned short* __restrict__ qimg, const unsigned short* __restrict__ kimg,
    const float* __restrict__ vin, float* __restrict__ vout,
    int L, int nblk,
    const float* __restrict__ peW, const float* __restrict__ Gp,
    const float* __restrict__ Bp2, const float* __restrict__ Mp,
    const float* __restrict__ Vp, const float* __restrict__ v0pm,
    float* __restrict__ xcur) {
  constexpr int B2 = B * B;
  constexpr int B3 = B * B * B;
  constexpr int NT = (B3 + 15) / 16;
  constexpr int MTW = (NT + 3) / 4;
  constexpr int SVS = 36;  // sv row stride (floats), 16B-aligned quads, non-pow2 banks
  __shared__ float slab[3 * B2 * B * B];
  __shared__ float sv[B3 * SVS];
  int tid = threadIdx.x;
  int w = tid >> 6, lane = tid & 63;
  int bid = blockIdx.x;
  int bh = bid / nblk;
  int blk = bid - bh * nblk;
  int hi = blk / S, lo = blk - hi * S;
  int base0 = hi * B3 * S + lo;
  int bI = bh >> 3, nh = bh & 7;
  int cl = lane & 15, r4 = lane >> 4;

  // v -> LDS, float4 (4 channels per thread)
  for (int t = tid; t < B3 * 8; t += 256) {
    int cq = t & 7, idx = t >> 3;
    *(f32x4*)(&sv[idx * SVS + cq * 4]) = *(const f32x4*)(
        vin + ((size_t)bI * L + base0 + idx * S) * VROW + nh * HDd + cq * 4);
  }

  short8 kh[MTW][2], qh[NT][2];
#pragma unroll
  for (int m = 0; m < MTW; m++) {
    int idx = (w * MTW + m) * 16 + cl;
    if (idx > B3 - 1) idx = B3 - 1;
    size_t row = ((size_t)bh * L + base0 + idx * S) * QROW;
#pragma unroll
    for (int kt = 0; kt < 2; kt++)
      kh[m][kt] = *(const short8*)(kimg + row + kt * 32 + r4 * 8);
  }
#pragma unroll
  for (int nt = 0; nt < NT; nt++) {
    int idx = nt * 16 + cl;
    if (idx > B3 - 1) idx = B3 - 1;
    size_t row = ((size_t)bh * L + base0 + idx * S) * QROW;
#pragma unroll
    for (int kt = 0; kt < 2; kt++)
      qh[nt][kt] = *(const short8*)(qimg + row + kt * 32 + r4 * 8);
  }
  f32x4 C[MTW][NT] = {};
#pragma unroll
  for (int kt = 0; kt < 2; kt++)
#pragma unroll
    for (int m = 0; m < MTW; m++)
#pragma unroll
      for (int nt = 0; nt < NT; nt++)
        C[m][nt] = __builtin_amdgcn_mfma_f32_16x16x32_bf16(kh[m][kt], qh[nt][kt], C[m][nt], 0, 0, 0);
#pragma unroll
  for (int m = 0; m < MTW; m++)
#pragma unroll
    for (int nt = 0; nt < NT; nt++)
#pragma unroll
      for (int rr = 0; rr < 4; rr++) {
        int J = (w * MTW + m) * 16 + r4 * 4 + rr;
        int j = nt * 16 + cl;
        if (J < B3 && j < B3) {
          float val = C[m][nt][rr];
          int A2 = J / B2, Jr = J - A2 * B2, A1 = Jr / B, A0 = Jr - A1 * B;
          int a2 = j / B2, jr = j - a2 * B2, a1 = jr / B, a0 = jr - a1 * B;
          if (A1 == a1 && A0 == a0) slab[((0 * B2 + (a1 * B + a0)) * B + A2) * B + a2] = val;
          if (A2 == a2 && A0 == a0) slab[((1 * B2 + (a2 * B + a0)) * B + A1) * B + a1] = val;
          if (A2 == a2 && A1 == a1) slab[((2 * B2 + (a2 * B + a1)) * B + A0) * B + a0] = val;
        }
      }
  __syncthreads();
  if (tid < 3 * B2) {
    float* bw = &slab[tid * B * B];
#pragma unroll
    for (int J = 0; J < B; J++) {
      float mx = bw[J * B];
#pragma unroll
      for (int j = 1; j < B; j++) mx = fmaxf(mx, bw[J * B + j]);
      float sum = 0.f;
      float e[B];
#pragma unroll
      for (int j = 0; j < B; j++) {
        e[j] = __expf(bw[J * B + j] - mx);
        sum += e[j];
      }
      float inv = 1.f / sum;
#pragma unroll
      for (int j = 0; j < B; j++) bw[J * B + j] = e[j] * inv;
    }
  }
  __syncthreads();
  int c = tid & 31, slot = tid >> 5;
  for (int lvl = 0; lvl < 3; lvl++) {
    for (int g = slot; g < B2; g += 8) {
      int ghi = g / B, glo = g - ghi * B;
      const float* wrow = &slab[(lvl * B2 + g) * B * B];
      float vvals[B], outs[B];
#pragma unroll
      for (int j = 0; j < B; j++) {
        int pid = (lvl == 0) ? (j * B2 + g) : (lvl == 1) ? (ghi * B2 + j * B + glo) : (g * B + j);
        vvals[j] = sv[pid * SVS + c];
      }
#pragma unroll
      for (int J = 0; J < B; J++) {
        float a = 0.f;
#pragma unroll
        for (int j = 0; j < B; j++) a += wrow[J * B + j] * vvals[j];
        outs[J] = a;
      }
#pragma unroll
      for (int J = 0; J < B; J++) {
        int pid = (lvl == 0) ? (J * B2 + g) : (lvl == 1) ? (ghi * B2 + J * B + glo) : (g * B + J);
        sv[pid * SVS + c] = outs[J];
      }
    }
    __syncthreads();
  }
  if (!FUSE) {
    for (int t = tid; t < B3 * 8; t += 256) {
      int cq = t & 7, idx = t >> 3;
      *(f32x4*)(vout + ((size_t)bI * L + base0 + idx * S) * VROW + nh * HDd + cq * 4) =
          *(const f32x4*)(&sv[idx * SVS + cq * 4]);
    }
  } else {
    int cq = tid & 7, slot2 = tid >> 3;
    int ch0 = nh * HDd + cq * 4;
    float pw0[4], pw1[4], pw2[4], ss[4], sh[4];
#pragma unroll
    for (int j = 0; j < 4; j++) {
      int ch = ch0 + j;
      pw0[j] = peW[ch * 3 + 0];
      pw1[j] = peW[ch * 3 + 1];
      pw2[j] = peW[ch * 3 + 2];
      ss[j] = Gp[ch] * rsqrtf(Vp[ch] + 1e-5f);
      sh[j] = Bp2[ch] - Mp[ch] * ss[j];
    }
    for (int idx = slot2; idx < B3; idx += 32) {
      int l = base0 + idx;  // S == 1 in FUSE passes
      if (l >= CW) continue;
      size_t row = ((size_t)bI * L + l) * VROW + ch0;
      f32x4 mid = *(const f32x4*)(v0pm + row);
      f32x4 left = {0.f, 0.f, 0.f, 0.f}, right = {0.f, 0.f, 0.f, 0.f};
      if (l > 0) left = *(const f32x4*)(v0pm + row - VROW);
      if (l + 1 < L) right = *(const f32x4*)(v0pm + row + VROW);
      float* xp = xcur + ((size_t)bI * CW + l) * CC + ch0;
      f32x4 x4 = *(f32x4*)xp;
#pragma unroll
      for (int j = 0; j < 4; j++) {
        float pe = (left[j] * pw0[j] + mid[j] * pw1[j] + right[j] * pw2[j]) * ss[j] + sh[j];
        x4[j] += sv[idx * SVS + cq * 4 + j] + pe;
      }
      *(f32x4*)xp = x4;
    }
  }
}

extern "C" void kernel_launch(void* const* d_in, const int* in_sizes, int n_in,
                              void* d_out, int out_size, void* d_ws, size_t ws_size,
                              hipStream_t stream) {
  const float* x = (const float*)d_in[0];
  const float* qk_W = (const float*)d_in[1];
  const float* qk_g = (const float*)d_in[2];
  const float* qk_b = (const float*)d_in[3];
  const float* qk_m = (const float*)d_in[4];
  const float* qk_v = (const float*)d_in[5];
  const float* v_W = (const float*)d_in[6];
  const float* v_g = (const float*)d_in[7];
  const float* v_b = (const float*)d_in[8];
  const float* v_m = (const float*)d_in[9];
  const float* v_v = (const float*)d_in[10];
  const float* pe_W = (const float*)d_in[11];
  const float* pe_g = (const float*)d_in[12];
  const float* pe_b = (const float*)d_in[13];
  const float* pe_m = (const float*)d_in[14];
  const float* pe_v = (const float*)d_in[15];
  const float* proj_W = (const float*)d_in[16];
  const float* proj_g = (const float*)d_in[17];
  const float* proj_b = (const float*)d_in[18];
  const float* proj_m = (const float*)d_in[19];
  const float* proj_v = (const float*)d_in[20];

  char* ws = (char*)d_ws;
  size_t off = 0;
  auto alloc = [&](size_t bytes) {
    char* p = ws + off;
    off += (bytes + 255) & ~(size_t)255;
    return (void*)p;
  };
  const int Lmax = 4096;
  const int P = CB * CW;
  const int ptiles = (P + 127) / 128;      // 98
  float* xcur = (float*)alloc((size_t)CB * CW * CC * 4);
  unsigned short* qimg = (unsigned short*)alloc((size_t)CB * NHh * Lmax * QROW * 2);
  unsigned short* kimg = (unsigned short*)alloc((size_t)CB * NHh * Lmax * QROW * 2);
  float* v0pm = (float*)alloc((size_t)CB * Lmax * VROW * 4);
  float* vA = (float*)alloc((size_t)CB * Lmax * VROW * 4);
  unsigned short* Ximg = (unsigned short*)alloc((size_t)ptiles * 32768 * 2);  // 6.4 MB
  unsigned short* Wimg0 = (unsigned short*)alloc((size_t)10 * 8 * 8192 * 2);
  unsigned short* Wimg1 = (unsigned short*)alloc((size_t)10 * 8 * 8192 * 2);
  unsigned short* Wimg2 = (unsigned short*)alloc((size_t)2 * 8 * 8192 * 2);
  (void)ws_size;

  // all weight staging in one launch
  prep_w_all<<<(2816 * 32 + 255) / 256, 256, 0, stream>>>(qk_W, v_W, proj_W,
                                                          Wimg0, Wimg1, Wimg2);
  // transpose + direct Ximg emit (replaces prep_x #1)
  {
    dim3 gt((CW + 63) / 64, 4, CB);
    transpose_x<<<gt, 256, 0, stream>>>(x, xcur, Ximg);
  }

  const int pgroups8 = (ptiles + 7) / 8;   // 13
  const int ptiles64 = (P + 63) / 64;      // 196
  const int pg64 = (ptiles64 + 7) / 8;     // 25
  const int gemmBlocks = 8 * pgroups8 * 10;
  const int Ls[2] = {3125, 4096};
  const unsigned short* Wimgs[2] = {Wimg0, Wimg1};
  for (int blk = 0; blk < 2; blk++) {
    int L = Ls[blk];
    if (blk == 1) {
      dim3 gx(ptiles, 4);
      prep_x<<<gx, 256, 0, stream>>>(xcur, Ximg, P);
    }
    int padBlocks = (L > CW) ? CB * (L - CW) : 0;
    gemm_qkv<<<gemmBlocks + padBlocks, 256, 0, stream>>>(
        Wimgs[blk], Ximg, qk_g + blk * 1024, qk_b + blk * 1024, qk_m + blk * 1024,
        qk_v + blk * 1024, v_g + blk * CC, v_b + blk * CC, v_m + blk * CC,
        v_v + blk * CC, qimg, kimg, v0pm, L, P, 10, ptiles, gemmBlocks);

    const float* peWb = pe_W + (size_t)blk * CC * 3;
    const float* peG = pe_g + blk * CC;
    const float* peB = pe_b + blk * CC;
    const float* peM = pe_m + blk * CC;
    const float* peV = pe_v + blk * CC;
    if (blk == 0) {
      // base 5: levels 0,1 (pair, s2=125) then levels 2,3,4 (tri, S=1) + FUSE
      int bpb = L / 25;  // 125
      attn_mfma<5, true, true><<<(CB * NHh * bpb) / 4, 256, 0, stream>>>(
          qimg, kimg, v0pm, vA, L, 125, bpb);
      int nblk = L / 125;  // 25
      attn_tri<5, 1, true><<<CB * NHh * nblk, 256, 0, stream>>>(
          qimg, kimg, vA, nullptr, L, nblk, peWb, peG, peB, peM, peV, v0pm, xcur);
    } else {
      // base 4: levels 0,1,2 (tri, S=64) then levels 3,4,5 (tri, S=1) + FUSE
      int nblk = L / 64;  // 64
      attn_tri<4, 64, false><<<CB * NHh * nblk, 256, 0, stream>>>(
          qimg, kimg, v0pm, vA, L, nblk, nullptr, nullptr, nullptr, nullptr,
          nullptr, nullptr, nullptr);
      attn_tri<4, 1, true><<<CB * NHh * nblk, 256, 0, stream>>>(
          qimg, kimg, vA, nullptr, L, nblk, peWb, peG, peB, peM, peV, v0pm, xcur);
    }
  }
  {
    dim3 gx(ptiles, 4);
    prep_x<<<gx, 256, 0, stream>>>(xcur, Ximg, P);
    gemm_proj<<<8 * pg64 * 2, 256, 0, stream>>>(
        Wimg2, Ximg, proj_g, proj_b, proj_m, proj_v, (float*)d_out, P, 2, ptiles64);
  }
}